// Round 4
// baseline (455.509 us; speedup 1.0000x reference)
//
#include <hip/hip_runtime.h>
#include <cstdint>
#include <cstddef>

#define KIN 300
#define KPAD 320
#define HIDDEN 128
#define BSZ 256
#define TSZ 512

// Phase-1 LDS row stride (shorts). 332*2/4 = 166 ≡ 6 (mod 32): bank spread.
#define ASTR 332
// Phase-1 epilogue stage: per-t_loc block = 16 u-groups x 136 shorts.
#define ST1 2176
// Scan ht row stride (shorts): 272 B = 16-B aligned; b128 reads land exactly
// 8 dwords/bank (minimum), b64 writes 4/bank -> balanced, conflict-free.
#define HSTR 136

typedef __attribute__((ext_vector_type(8))) short short8;
typedef __attribute__((ext_vector_type(4))) short s16x4;
typedef __attribute__((ext_vector_type(4))) float f32x4;

__device__ __forceinline__ short f2bf(float f) {
  uint32_t u = __builtin_bit_cast(uint32_t, f);
  u = (u + 0x7FFFu + ((u >> 16) & 1u)) >> 16;
  return (short)u;
}
__device__ __forceinline__ float bf2f(short s) {
  uint32_t u = ((uint32_t)(uint16_t)s) << 16;
  return __builtin_bit_cast(float, u);
}
__device__ __forceinline__ float bflo(uint32_t u) {
  return __builtin_bit_cast(float, u << 16);
}
__device__ __forceinline__ float bfhi(uint32_t u) {
  return __builtin_bit_cast(float, u & 0xFFFF0000u);
}
// HW packed f32->bf16 RNE convert: lo = bf16(a), hi = bf16(b). 1 inst vs ~10.
__device__ __forceinline__ uint32_t pack2bf(float a, float b) {
  uint32_t r;
  asm("v_cvt_pk_bf16_f32 %0, %1, %2" : "=v"(r) : "v"(a), "v"(b));
  return r;
}
// tanh(x) = 1 - 2/(exp2(x*2*log2e)+1); exact at +/-1 extremes, 5 VALU inst.
__device__ __forceinline__ float tanhf_fast(float v) {
  const float e = __builtin_amdgcn_exp2f(v * 2.88539008177793f);
  return fmaf(-2.0f, __builtin_amdgcn_rcpf(e + 1.0f), 1.0f);
}
// Barrier that waits LDS ops but leaves global/DMA (vmcnt) in flight.
__device__ __forceinline__ void barrier_lds() {
  asm volatile("s_waitcnt lgkmcnt(0)\n\ts_barrier" ::: "memory");
}
__device__ __forceinline__ void barrier_all() {
  asm volatile("s_waitcnt vmcnt(0) lgkmcnt(0)\n\ts_barrier" ::: "memory");
}
// async 16B/lane global->LDS DMA: lds dst = uniform base + lane*16
__device__ __forceinline__ void dma16(const short* g, short* l) {
  __builtin_amdgcn_global_load_lds(
      (const __attribute__((address_space(1))) void*)g,
      (__attribute__((address_space(3))) void*)l, 16, 0, 0);
}

// ---------------- Phase 0: W_ih -> bf16, K zero-padded to 320 --------------
__global__ __launch_bounds__(256) void wcvt_bf16(const float* __restrict__ W,
                                                 short* __restrict__ W16) {
  const int i = blockIdx.x * 256 + threadIdx.x;
  if (i >= HIDDEN * KPAD) return;
  const int n = i / KPAD, k = i % KPAD;
  W16[i] = (k < KIN) ? f2bf(W[n * KIN + k]) : (short)0;
}

// ---------------- Phase 1: xp = x @ W_ih^T + bias, DMA-native layout -------
// Block = 16 batches x 4 timesteps = 64 rows; x row-tile staged in LDS ONCE
// (bf16, 43 KB) -> x read exactly 1x from HBM.
// Epilogue NOW emits the 4-wave scan's layout: per (t,bg) payload is
// [u][b][8] where u = 4*(h>>5) + ((h&15)>>2): the 8 shorts per (u,b) are
// h rows {32W+4Q+r} then {32W+16+4Q+r} -> one b128 per lane per step in scan.
__global__ __launch_bounds__(256) void xp_gemm_mfma(
    const float* __restrict__ x, const short* __restrict__ W16,
    const float* __restrict__ b_ih, const float* __restrict__ b_hh,
    short* __restrict__ xp16) {
  __shared__ __align__(16) short As[64 * ASTR];  // 43 KB; reused as epilogue stage
  const int tid = threadIdx.x;
  const int lane = tid & 63, w = tid >> 6;
  const int q = lane >> 4, c = lane & 15;
  const int bg = blockIdx.x & 15, tc = blockIdx.x >> 4;
  const int b0 = bg * 16, t0 = tc * 4;

  // ---- stage x tile (64 rows x 300 K) as bf16, padded stride ASTR ----
#pragma unroll
  for (int i = 0; i < 19; ++i) {
    const int f = tid + 256 * i;  // float4 index over 64*75
    if (f < 4800) {
      const int rr = f / 75;
      const int k4 = f - rr * 75;
      const int b_in = rr >> 2, t_loc = rr & 3;
      const float4 v = *(const float4*)(
          x + ((size_t)(b0 + b_in) * TSZ + t0 + t_loc) * KIN + k4 * 4);
      uint2 pv;
      pv.x = pack2bf(v.x, v.y);
      pv.y = pack2bf(v.z, v.w);
      *(uint2*)&As[rr * ASTR + k4 * 4] = pv;
    }
  }
  if (tid < 64) {  // zero-pad k = 300..319
    const uint2 z = {0u, 0u};
#pragma unroll
    for (int j = 0; j < 5; ++j) *(uint2*)&As[tid * ASTR + 300 + j * 4] = z;
  }
  __syncthreads();

  // wave w owns h-tiles {2w, 2w+1} x all 4 row-tiles
  f32x4 acc[2][4];
#pragma unroll
  for (int ht = 0; ht < 2; ++ht)
#pragma unroll
    for (int rt = 0; rt < 4; ++rt) acc[ht][rt] = (f32x4){0.f, 0.f, 0.f, 0.f};

  // A-frags (W16, L2-resident): lane (q,c) -> A[m=c][k=q*8+j]
  const short* wp0 = W16 + (size_t)((2 * w + 0) * 16 + c) * KPAD + q * 8;
  const short* wp1 = W16 + (size_t)((2 * w + 1) * 16 + c) * KPAD + q * 8;
  // B-frag LDS base for this lane
  const short* bqp = &As[c * ASTR + q * 8];
  short8 af[2][2];
  short8 bq[2][4];
  af[0][0] = *(const short8*)(wp0);
  af[0][1] = *(const short8*)(wp1);
#pragma unroll
  for (int rt = 0; rt < 4; ++rt)
    bq[0][rt] = *(const short8*)(bqp + rt * 16 * ASTR);
#pragma unroll
  for (int kc = 0; kc < 10; ++kc) {
    const int cur = kc & 1;
    if (kc < 9) {
      af[cur ^ 1][0] = *(const short8*)(wp0 + (kc + 1) * 32);
      af[cur ^ 1][1] = *(const short8*)(wp1 + (kc + 1) * 32);
#pragma unroll
      for (int rt = 0; rt < 4; ++rt)
        bq[cur ^ 1][rt] = *(const short8*)(bqp + rt * 16 * ASTR + (kc + 1) * 32);
    }
#pragma unroll
    for (int ht = 0; ht < 2; ++ht)
#pragma unroll
      for (int rt = 0; rt < 4; ++rt)
        acc[ht][rt] = __builtin_amdgcn_mfma_f32_16x16x32_bf16(
            af[cur][ht], bq[cur][rt], acc[ht][rt], 0, 0, 0);
  }
  __syncthreads();  // all B-frag reads done; As becomes the stage buffer

  // ---- epilogue: bias, pack, LDS transpose to [t][u][b][8] (padded) ----
  float4 bsum[2];
#pragma unroll
  for (int ht = 0; ht < 2; ++ht) {
    const int h0 = (2 * w + ht) * 16 + q * 4;
    const float4 bi = *(const float4*)(b_ih + h0);
    const float4 bh = *(const float4*)(b_hh + h0);
    bsum[ht] = make_float4(bi.x + bh.x, bi.y + bh.y, bi.z + bh.z, bi.w + bh.w);
  }
  // stage layout: t stride ST1, u stride 136, b stride 8, mt offset 4
#pragma unroll
  for (int ht = 0; ht < 2; ++ht) {
    const int g = (2 * w + ht) * 4 + q;          // h-group = h/4, g in [0,32)
    const int u = 4 * (g >> 3) + (g & 3);        // scan u-index
    const int mt = (g >> 2) & 1;                 // scan m-tile parity
#pragma unroll
    for (int rt = 0; rt < 4; ++rt) {
      const int b_in = rt * 4 + (c >> 2);
      const int t_loc = c & 3;
      uint2 pv;
      pv.x = pack2bf(acc[ht][rt][0] + bsum[ht].x, acc[ht][rt][1] + bsum[ht].y);
      pv.y = pack2bf(acc[ht][rt][2] + bsum[ht].z, acc[ht][rt][3] + bsum[ht].w);
      *(uint2*)&As[t_loc * ST1 + u * 136 + b_in * 8 + mt * 4] = pv;
    }
  }
  __syncthreads();
  // ---- coalesced copy-out: per t_loc a dense 4 KB region ----
  // thread tid covers u = tid>>4, b = tid&15 (8 shorts = both mt halves)
#pragma unroll
  for (int i = 0; i < 4; ++i) {
    const int4 vv =
        *(const int4*)&As[i * ST1 + (tid >> 4) * 136 + (tid & 15) * 8];
    *(int4*)(xp16 + ((size_t)(t0 + i) * 16 + bg) * 2048 + tid * 8) = vv;
  }
}

// ---------------- Phase 2: MFMA-batched scan + fused FC --------------------
// NEW: 16 blocks x 256 threads (4 waves), wave w owns h-out rows [32w,32w+32).
// Rationale (r3 PMC): the step was LDS-instruction-throughput-bound — the
// 8-wave h broadcast cost 64 ds_read_b64/step on the CU-shared LDS pipe
// (~6-12 cyc/inst). 4 waves + b128 cuts it to 16 reads + 8 writes + 8 xs
// reads ≈ 28 insts/step. ht is k-linear [parity][batch][k] stride HSTR=136:
// 16-B aligned, b128 reads land exactly 8 dwords/bank (the b128 minimum).
// xs is [u][b][8] so each lane's per-step xp init is ONE b128.
__global__ __launch_bounds__(256, 1) void rnn_scan_dma(
    const short* __restrict__ xp16, const float* __restrict__ Whh,
    const float* __restrict__ fc_w, const float* __restrict__ fc_b,
    float* __restrict__ out) {
  __shared__ __align__(16) short xs[2][8][2048];   // 64 KB
  __shared__ __align__(16) short ht[2][16][HSTR];  // 8.5 KB, k-linear
  const int tid = threadIdx.x;
  const int lane = tid & 63, w = tid >> 6;      // w = 0..3
  const int q = lane >> 4, c = lane & 15;
  const int bg = blockIdx.x;

  // W_hh A-frags: wave w owns rows [32w,32w+32), split as mt in {0,1}.
  short8 aw[2][4];
#pragma unroll
  for (int mt = 0; mt < 2; ++mt)
#pragma unroll
    for (int kc = 0; kc < 4; ++kc) {
      const float* src =
          Whh + (size_t)(32 * w + 16 * mt + c) * HIDDEN + kc * 32 + q * 8;
      const float4 v0 = *(const float4*)(src);
      const float4 v1 = *(const float4*)(src + 4);
      short8 t;
      t[0] = f2bf(v0.x); t[1] = f2bf(v0.y); t[2] = f2bf(v0.z); t[3] = f2bf(v0.w);
      t[4] = f2bf(v1.x); t[5] = f2bf(v1.y); t[6] = f2bf(v1.z); t[7] = f2bf(v1.w);
      aw[mt][kc] = t;
    }

  // h0 = 0
  {
    uint32_t* z = (uint32_t*)&ht[0][0][0];
    for (int i = tid; i < 2176; i += 256) z[i] = 0;
  }

  // DMA issue: wave w covers chunk-steps {2w, 2w+1}, 4 x 1KB insts each
#define ISSUE_CHUNK(CH, BUF)                                                  \
  {                                                                           \
    _Pragma("unroll") for (int sr = 0; sr < 2; ++sr) {                        \
      const int s = 2 * w + sr;                                               \
      const short* srcb =                                                     \
          xp16 + ((size_t)((CH)*8 + s) * 16 + bg) * 2048 + lane * 8;          \
      _Pragma("unroll") for (int j = 0; j < 4; ++j)                           \
          dma16(srcb + j * 512, &xs[BUF][s][j * 512]);                        \
    }                                                                         \
  }

  ISSUE_CHUNK(0, 0)
  barrier_all();  // chunk-0 DMA landed; ht zero + everyone ready

  const int xsoff = (4 * w + q) * 128 + c * 8;  // one b128 per step per lane
  const f32x4 zero4 = {0.f, 0.f, 0.f, 0.f};

  for (int cc = 0; cc < 64; ++cc) {
    const int buf = cc & 1;
    if (cc + 1 < 64) ISSUE_CHUNK(cc + 1, buf ^ 1)
    // preload the whole chunk's xp for this lane (h-independent, dbuf'd)
    uint4 us[8];
#pragma unroll
    for (int s = 0; s < 8; ++s) us[s] = *(const uint4*)&xs[buf][s][xsoff];
#pragma unroll
    for (int s = 0; s < 8; ++s) {
      const int rb = s & 1;  // global t = cc*8+s; cc even so parity = s&1
      const short* bp = &ht[rb][c][q * 8];
      const short8 bh0 = *(const short8*)(bp + 0);
      const short8 bh1 = *(const short8*)(bp + 32);
      const short8 bh2 = *(const short8*)(bp + 64);
      const short8 bh3 = *(const short8*)(bp + 96);
      f32x4 p0 = {bflo(us[s].x), bfhi(us[s].x), bflo(us[s].y), bfhi(us[s].y)};
      f32x4 p1 = {bflo(us[s].z), bfhi(us[s].z), bflo(us[s].w), bfhi(us[s].w)};
      f32x4 r0 = zero4, r1 = zero4;
      p0 = __builtin_amdgcn_mfma_f32_16x16x32_bf16(aw[0][0], bh0, p0, 0, 0, 0);
      r0 = __builtin_amdgcn_mfma_f32_16x16x32_bf16(aw[0][2], bh2, r0, 0, 0, 0);
      p1 = __builtin_amdgcn_mfma_f32_16x16x32_bf16(aw[1][0], bh0, p1, 0, 0, 0);
      r1 = __builtin_amdgcn_mfma_f32_16x16x32_bf16(aw[1][2], bh2, r1, 0, 0, 0);
      p0 = __builtin_amdgcn_mfma_f32_16x16x32_bf16(aw[0][1], bh1, p0, 0, 0, 0);
      r0 = __builtin_amdgcn_mfma_f32_16x16x32_bf16(aw[0][3], bh3, r0, 0, 0, 0);
      p1 = __builtin_amdgcn_mfma_f32_16x16x32_bf16(aw[1][1], bh1, p1, 0, 0, 0);
      r1 = __builtin_amdgcn_mfma_f32_16x16x32_bf16(aw[1][3], bh3, r1, 0, 0, 0);
      const f32x4 s0 = p0 + r0;
      const f32x4 s1 = p1 + r1;
      uint2 w0, w1;
      w0.x = pack2bf(tanhf_fast(s0[0]), tanhf_fast(s0[1]));
      w0.y = pack2bf(tanhf_fast(s0[2]), tanhf_fast(s0[3]));
      w1.x = pack2bf(tanhf_fast(s1[0]), tanhf_fast(s1[1]));
      w1.y = pack2bf(tanhf_fast(s1[2]), tanhf_fast(s1[3]));
      *(uint2*)&ht[rb ^ 1][c][32 * w + 4 * q] = w0;       // mt = 0 rows
      *(uint2*)&ht[rb ^ 1][c][32 * w + 16 + 4 * q] = w1;  // mt = 1 rows
      barrier_lds();
    }
    barrier_all();  // next chunk's DMA (issued ~8 steps ago) must be landed
  }
#undef ISSUE_CHUNK

  // h_last in ht[0] (t=511 wrote rb^1 = 0), k-linear layout. FC: 32 outs.
  if (tid < 32) {
    const int bi = tid >> 1, cls = tid & 1;
    float s = fc_b[cls];
    const float* fw = fc_w + cls * HIDDEN;
#pragma unroll 8
    for (int k = 0; k < HIDDEN; k += 4) {
      s = fmaf(bf2f(ht[0][bi][k + 0]), fw[k + 0], s);
      s = fmaf(bf2f(ht[0][bi][k + 1]), fw[k + 1], s);
      s = fmaf(bf2f(ht[0][bi][k + 2]), fw[k + 2], s);
      s = fmaf(bf2f(ht[0][bi][k + 3]), fw[k + 3], s);
    }
    out[(bg * 16 + bi) * 2 + cls] = s;
  }
}

extern "C" void kernel_launch(void* const* d_in, const int* in_sizes, int n_in,
                              void* d_out, int out_size, void* d_ws, size_t ws_size,
                              hipStream_t stream) {
  const float* x    = (const float*)d_in[0];
  const float* W_ih = (const float*)d_in[1];
  const float* W_hh = (const float*)d_in[2];
  const float* b_ih = (const float*)d_in[3];
  const float* b_hh = (const float*)d_in[4];
  const float* fc_w = (const float*)d_in[5];
  const float* fc_b = (const float*)d_in[6];
  short* xp16 = (short*)d_ws;                         // 32 MiB bf16 [T][16bg][2048]
  short* W16  = (short*)((char*)d_ws + (33u << 20));  // 80 KB bf16 [128][320]
  float* out  = (float*)d_out;

  wcvt_bf16<<<(HIDDEN * KPAD + 255) / 256, 256, 0, stream>>>(W_ih, W16);
  xp_gemm_mfma<<<16 * (TSZ / 4), 256, 0, stream>>>(x, W16, b_ih, b_hh, xp16);
  rnn_scan_dma<<<16, 256, 0, stream>>>(xp16, W_hh, fc_w, fc_b, out);
}